// Round 1
// baseline (12240.082 us; speedup 1.0000x reference)
//
#include <hip/hip_runtime.h>
#include <hip/hip_bf16.h>

// LSTM decoder: B=256, H=1024, L=2, T=128.
// Strategy: spectral-norm prep (sigma = ||W (W^T u)|| / ||W^T u||) folded into a
// one-time fp32->fp16 weight conversion; 256 sequential cell kernels, each an
// MFMA f16 GEMM (gates = [x|h] @ Wcomb^T) + fused LSTM elementwise update.

typedef _Float16 half8 __attribute__((ext_vector_type(8)));
typedef _Float16 half4 __attribute__((ext_vector_type(4)));
typedef float f32x4 __attribute__((ext_vector_type(4)));

#define HSZ 1024
#define BSZ 256
#define TSZ 128

// ---------------- prep: vraw = W^T u (two-stage deterministic) ----------------
__global__ __launch_bounds__(256) void prep_vraw1(
    const float* __restrict__ Wih, const float* __restrict__ Whh,
    const float* __restrict__ uih, const float* __restrict__ uhh,
    float* __restrict__ vpart) {
  int bx = blockIdx.x;                 // 256 blocks: m(4) x rc(16) x jc(4)
  int m = bx >> 6, rc = (bx >> 2) & 15, jc = bx & 3;
  int j = jc * 256 + threadIdx.x;
  const float* W = (m < 2 ? Wih : Whh) + ((size_t)(m & 1) << 22);
  const float* u = (m < 2 ? uih : uhh) + (m & 1) * 4096;
  float acc = 0.f;
  int rbase = rc * 256;
  for (int r = 0; r < 256; ++r)
    acc += W[(size_t)(rbase + r) * 1024 + j] * u[rbase + r];
  vpart[(m * 16 + rc) * 1024 + j] = acc;
}

__global__ __launch_bounds__(256) void prep_vraw2(
    const float* __restrict__ vpart, float* __restrict__ vraw) {
  int i = blockIdx.x * 256 + threadIdx.x;   // 0..4095 -> m*1024+j
  int m = i >> 10;
  float acc = 0.f;
  for (int rc = 0; rc < 16; ++rc)
    acc += vpart[(m * 16 + rc) * 1024 + (i & 1023)];
  vraw[i] = acc;
}

// ---------------- prep: wv = W @ vraw ----------------
__global__ __launch_bounds__(256) void prep_wv(
    const float* __restrict__ Wih, const float* __restrict__ Whh,
    const float* __restrict__ vraw, float* __restrict__ wv) {
  int m = blockIdx.y;
  int w = threadIdx.x >> 6, l = threadIdx.x & 63;
  int r = blockIdx.x * 4 + w;
  const float* W = (m < 2 ? Wih : Whh) + ((size_t)(m & 1) << 22) + (size_t)r * 1024;
  const float* v = vraw + m * 1024;
  float acc = 0.f;
  for (int it = 0; it < 4; ++it) {
    int j = it * 256 + l * 4;
    float4 w4 = *(const float4*)(W + j);
    float4 v4 = *(const float4*)(v + j);
    acc += w4.x * v4.x + w4.y * v4.y + w4.z * v4.z + w4.w * v4.w;
  }
  for (int o = 32; o; o >>= 1) acc += __shfl_down(acc, o);
  if (l == 0) wv[m * 4096 + r] = acc;
}

// ---------------- prep: inv_sigma = ||vraw|| / ||wv|| ----------------
__global__ __launch_bounds__(256) void prep_sig(
    const float* __restrict__ vraw, const float* __restrict__ wv,
    float* __restrict__ invsig) {
  int m = blockIdx.x, tid = threadIdx.x;
  __shared__ float red[256];
  float sv = 0.f, sw = 0.f;
  for (int i = tid; i < 1024; i += 256) { float x = vraw[m * 1024 + i]; sv += x * x; }
  for (int i = tid; i < 4096; i += 256) { float x = wv[m * 4096 + i]; sw += x * x; }
  red[tid] = sv; __syncthreads();
  for (int s = 128; s; s >>= 1) { if (tid < s) red[tid] += red[tid + s]; __syncthreads(); }
  float svt = red[0]; __syncthreads();
  red[tid] = sw; __syncthreads();
  for (int s = 128; s; s >>= 1) { if (tid < s) red[tid] += red[tid + s]; __syncthreads(); }
  if (tid == 0) invsig[m] = sqrtf(svt / red[0]);
}

// ---------------- prep: Wcomb f16 = [Wih | Whh] * inv_sigma ----------------
__global__ __launch_bounds__(256) void prep_wcomb(
    const float* __restrict__ Wih, const float* __restrict__ Whh,
    const float* __restrict__ invsig, _Float16* __restrict__ wcomb) {
  size_t idx4 = ((size_t)blockIdx.x * 256 + threadIdx.x) * 4;
  if (idx4 >= (size_t)2 * 4096 * 2048) return;
  int l = (int)(idx4 >> 23);
  int rem = (int)(idx4 & ((1u << 23) - 1));
  int r = rem >> 11, k = rem & 2047;
  const float* src; float s;
  if (k < 1024) { src = Wih + ((size_t)l << 22) + (size_t)r * 1024 + k; s = invsig[l]; }
  else          { src = Whh + ((size_t)l << 22) + (size_t)r * 1024 + (k - 1024); s = invsig[2 + l]; }
  float4 v = *(const float4*)src;
  half4 o = { (_Float16)(v.x * s), (_Float16)(v.y * s),
              (_Float16)(v.z * s), (_Float16)(v.w * s) };
  *(half4*)(wcomb + idx4) = o;
}

__global__ __launch_bounds__(256) void prep_bias(
    const float* __restrict__ b_ih, const float* __restrict__ b_hh,
    float* __restrict__ bias) {
  int i = blockIdx.x * 256 + threadIdx.x;
  if (i < 8192) bias[i] = b_ih[i] + b_hh[i];
}

__global__ __launch_bounds__(256) void prep_init(
    const float* __restrict__ x0, const float* __restrict__ h0,
    const float* __restrict__ c0, _Float16* __restrict__ Xinit,
    _Float16* __restrict__ H0p0, _Float16* __restrict__ H1p0,
    float* __restrict__ C0, float* __restrict__ C1) {
  int i = blockIdx.x * 256 + threadIdx.x;   // 0..262143
  Xinit[i] = (_Float16)x0[i];
  H0p0[i]  = (_Float16)h0[i];
  H1p0[i]  = (_Float16)h0[262144 + i];
  C0[i] = c0[i];
  C1[i] = c0[262144 + i];
}

// ---------------- the LSTM cell: gates GEMM + elementwise ----------------
// grid (64, 4): 64 h-col chunks of 16, 4 batch chunks of 64. 512 threads (8 waves).
// wave w: gate group wr = w&3 (16 gate rows), batch half wc = w>>2 (32 rows).
__global__ __launch_bounds__(512) void lstm_cell(
    const _Float16* __restrict__ W,     // [4096][2048] f16, pre-scaled
    const float* __restrict__ bias,     // [4096]
    const _Float16* __restrict__ xbuf,  // [256][1024] f16
    const _Float16* __restrict__ hbuf,  // [256][1024] f16
    float* __restrict__ cbuf,           // [256][1024] f32 (in-place)
    _Float16* __restrict__ hout,        // [256][1024] f16
    float* __restrict__ yout)           // null, or d_out + t*1024
{
  const int tid = threadIdx.x;
  const int l = tid & 63, w = tid >> 6;
  const int wr = w & 3, wc = w >> 2;
  const int lr = l & 15, lk = l >> 4;
  const int j0 = blockIdx.x * 16;
  const int bm0 = blockIdx.y * 64;

  // A fragment: W row = wr*1024 + j0 + lr (gate group wr, h-col j0+lr), k = lk*8..
  const _Float16* Arow = W + (size_t)(wr * 1024 + j0 + lr) * 2048 + lk * 8;
  // B fragments: act rows bm0 + wc*32 + {lr, 16+lr}
  const size_t boff0 = (size_t)(bm0 + wc * 32 + lr) * 1024 + lk * 8;
  const size_t boff1 = boff0 + (size_t)16 * 1024;

  f32x4 acc0 = {0.f, 0.f, 0.f, 0.f};
  f32x4 acc1 = {0.f, 0.f, 0.f, 0.f};

  const _Float16* bases[2] = { xbuf, hbuf };
#pragma unroll
  for (int hh = 0; hh < 2; ++hh) {
    const _Float16* actb = bases[hh];
    const _Float16* Ap = Arow + hh * 1024;
#pragma unroll 4
    for (int ks = 0; ks < 32; ++ks) {
      const int kb = ks * 32;
      half8 a  = *(const half8*)(Ap + kb);
      half8 b0 = *(const half8*)(actb + boff0 + kb);
      half8 b1 = *(const half8*)(actb + boff1 + kb);
      acc0 = __builtin_amdgcn_mfma_f32_16x16x32_f16(a, b0, acc0, 0, 0, 0);
      acc1 = __builtin_amdgcn_mfma_f32_16x16x32_f16(a, b1, acc1, 0, 0, 0);
    }
  }

  // exchange gates through LDS: rows = 4 gate groups x 16 h-cols, cols = 64 batch
  __shared__ float gl[64][65];
#pragma unroll
  for (int j = 0; j < 4; ++j) {
    int row = wr * 16 + lk * 4 + j;
    gl[row][wc * 32 + lr] = acc0[j];
    gl[row][wc * 32 + 16 + lr] = acc1[j];
  }
  __syncthreads();

  const int b = tid & 63, jq = tid >> 6;
#pragma unroll
  for (int jj = 0; jj < 2; ++jj) {
    const int j = jq + jj * 8;       // 0..15
    const int jg = j0 + j;
    float iv = gl[j][b]      + bias[jg];
    float fv = gl[16 + j][b] + bias[1024 + jg];
    float gv = gl[32 + j][b] + bias[2048 + jg];
    float ov = gl[48 + j][b] + bias[3072 + jg];
    const size_t idx = (size_t)(bm0 + b) * 1024 + jg;
    float c_old = cbuf[idx];
    float si = 1.f / (1.f + __expf(-iv));
    float sf = 1.f / (1.f + __expf(-fv));
    float so = 1.f / (1.f + __expf(-ov));
    float e2g = __expf(fminf(fmaxf(2.f * gv, -30.f), 30.f));
    float tg = (e2g - 1.f) / (e2g + 1.f);
    float cn = sf * c_old + si * tg;
    float e2c = __expf(fminf(fmaxf(2.f * cn, -30.f), 30.f));
    float tc = (e2c - 1.f) / (e2c + 1.f);
    float hn = so * tc;
    cbuf[idx] = cn;
    hout[idx] = (_Float16)hn;
    if (yout) yout[(size_t)(bm0 + b) * (TSZ * HSZ) + jg] = hn;
  }
}

extern "C" void kernel_launch(void* const* d_in, const int* in_sizes, int n_in,
                              void* d_out, int out_size, void* d_ws, size_t ws_size,
                              hipStream_t stream) {
  (void)in_sizes; (void)n_in; (void)out_size; (void)ws_size;
  const float* x0   = (const float*)d_in[0];
  const float* h0   = (const float*)d_in[1];
  const float* c0   = (const float*)d_in[2];
  const float* Wih  = (const float*)d_in[3];
  const float* Whh  = (const float*)d_in[4];
  const float* b_ih = (const float*)d_in[5];
  const float* b_hh = (const float*)d_in[6];
  const float* u_ih = (const float*)d_in[7];
  const float* u_hh = (const float*)d_in[8];
  float* out = (float*)d_out;

  char* ws = (char*)d_ws;
  size_t off = 0;
  auto alloc = [&](size_t bytes) -> void* {
    void* p = ws + off;
    off = (off + bytes + 255) & ~(size_t)255;
    return p;
  };
  _Float16* wcomb  = (_Float16*)alloc((size_t)2 * 4096 * 2048 * 2);
  float*    vpart  = (float*)alloc((size_t)4 * 16 * 1024 * 4);
  float*    vraw   = (float*)alloc((size_t)4 * 1024 * 4);
  float*    wv     = (float*)alloc((size_t)4 * 4096 * 4);
  float*    invsig = (float*)alloc(16);
  float*    bias   = (float*)alloc((size_t)2 * 4096 * 4);
  _Float16* Xinit  = (_Float16*)alloc((size_t)262144 * 2);
  _Float16* Hb[2][2];
  for (int a = 0; a < 2; ++a)
    for (int p = 0; p < 2; ++p)
      Hb[a][p] = (_Float16*)alloc((size_t)262144 * 2);
  float* Cb[2];
  Cb[0] = (float*)alloc((size_t)262144 * 4);
  Cb[1] = (float*)alloc((size_t)262144 * 4);

  prep_vraw1<<<256, 256, 0, stream>>>(Wih, Whh, u_ih, u_hh, vpart);
  prep_vraw2<<<16, 256, 0, stream>>>(vpart, vraw);
  prep_wv<<<dim3(1024, 4), 256, 0, stream>>>(Wih, Whh, vraw, wv);
  prep_sig<<<4, 256, 0, stream>>>(vraw, wv, invsig);
  prep_wcomb<<<16384, 256, 0, stream>>>(Wih, Whh, invsig, wcomb);
  prep_bias<<<32, 256, 0, stream>>>(b_ih, b_hh, bias);
  prep_init<<<1024, 256, 0, stream>>>(x0, h0, c0, Xinit, Hb[0][0], Hb[1][0], Cb[0], Cb[1]);

  _Float16* W0 = wcomb;
  _Float16* W1 = wcomb + (size_t)4096 * 2048;

  for (int t = 0; t < TSZ; ++t) {
    int p = t & 1;
    // layer 0: x = prev top-layer output (or initial input), h = H0[p] -> H0[p^1]
    lstm_cell<<<dim3(64, 4), 512, 0, stream>>>(
        W0, bias, (t == 0 ? Xinit : Hb[1][p]), Hb[0][p], Cb[0], Hb[0][p ^ 1], nullptr);
    // layer 1: x = H0[p^1], h = H1[p] -> H1[p^1]; writes fp32 output slice t
    lstm_cell<<<dim3(64, 4), 512, 0, stream>>>(
        W1, bias + 4096, Hb[0][p ^ 1], Hb[1][p], Cb[1], Hb[1][p ^ 1],
        out + (size_t)t * HSZ);
  }
}

// Round 2
// 3713.131 us; speedup vs baseline: 3.2964x; 3.2964x over previous
//
#include <hip/hip_runtime.h>
#include <hip/hip_bf16.h>

// LSTM decoder: B=256, H=1024, L=2, T=128.
// R2: LDS-staged MFMA cell kernel. 256 blocks x 256 threads; block tile =
// 64 gate-rows (16 h-cols x 4 gates) x 64 batch; BK=128 double-buffered via
// global_load_lds(16B) with pre-swizzled source (XOR granule^=(row&7));
// 4 waves of 32x32 register tiles; fused LSTM epilogue through LDS exchange.

typedef _Float16 half8 __attribute__((ext_vector_type(8)));
typedef _Float16 half4 __attribute__((ext_vector_type(4)));
typedef float f32x4 __attribute__((ext_vector_type(4)));

#define HSZ 1024
#define BSZ 256
#define TSZ 128

#define AS1 __attribute__((address_space(1)))
#define AS3 __attribute__((address_space(3)))

static __device__ __forceinline__ void gload16(const void* g, void* l) {
  __builtin_amdgcn_global_load_lds((const AS1 unsigned int*)g,
                                   (AS3 unsigned int*)l, 16, 0, 0);
}

// ---------------- prep: vraw = W^T u (two-stage deterministic) ----------------
__global__ __launch_bounds__(256) void prep_vraw1(
    const float* __restrict__ Wih, const float* __restrict__ Whh,
    const float* __restrict__ uih, const float* __restrict__ uhh,
    float* __restrict__ vpart) {
  int bx = blockIdx.x;                 // 256 blocks: m(4) x rc(16) x jc(4)
  int m = bx >> 6, rc = (bx >> 2) & 15, jc = bx & 3;
  int j = jc * 256 + threadIdx.x;
  const float* W = (m < 2 ? Wih : Whh) + ((size_t)(m & 1) << 22);
  const float* u = (m < 2 ? uih : uhh) + (m & 1) * 4096;
  float acc = 0.f;
  int rbase = rc * 256;
  for (int r = 0; r < 256; ++r)
    acc += W[(size_t)(rbase + r) * 1024 + j] * u[rbase + r];
  vpart[(m * 16 + rc) * 1024 + j] = acc;
}

__global__ __launch_bounds__(256) void prep_vraw2(
    const float* __restrict__ vpart, float* __restrict__ vraw) {
  int i = blockIdx.x * 256 + threadIdx.x;   // 0..4095 -> m*1024+j
  int m = i >> 10;
  float acc = 0.f;
  for (int rc = 0; rc < 16; ++rc)
    acc += vpart[(m * 16 + rc) * 1024 + (i & 1023)];
  vraw[i] = acc;
}

// ---------------- prep: wv = W @ vraw ----------------
__global__ __launch_bounds__(256) void prep_wv(
    const float* __restrict__ Wih, const float* __restrict__ Whh,
    const float* __restrict__ vraw, float* __restrict__ wv) {
  int m = blockIdx.y;
  int w = threadIdx.x >> 6, l = threadIdx.x & 63;
  int r = blockIdx.x * 4 + w;
  const float* W = (m < 2 ? Wih : Whh) + ((size_t)(m & 1) << 22) + (size_t)r * 1024;
  const float* v = vraw + m * 1024;
  float acc = 0.f;
  for (int it = 0; it < 4; ++it) {
    int j = it * 256 + l * 4;
    float4 w4 = *(const float4*)(W + j);
    float4 v4 = *(const float4*)(v + j);
    acc += w4.x * v4.x + w4.y * v4.y + w4.z * v4.z + w4.w * v4.w;
  }
  for (int o = 32; o; o >>= 1) acc += __shfl_down(acc, o);
  if (l == 0) wv[m * 4096 + r] = acc;
}

// ---------------- prep: inv_sigma = ||vraw|| / ||wv|| ----------------
__global__ __launch_bounds__(256) void prep_sig(
    const float* __restrict__ vraw, const float* __restrict__ wv,
    float* __restrict__ invsig) {
  int m = blockIdx.x, tid = threadIdx.x;
  __shared__ float red[256];
  float sv = 0.f, sw = 0.f;
  for (int i = tid; i < 1024; i += 256) { float x = vraw[m * 1024 + i]; sv += x * x; }
  for (int i = tid; i < 4096; i += 256) { float x = wv[m * 4096 + i]; sw += x * x; }
  red[tid] = sv; __syncthreads();
  for (int s = 128; s; s >>= 1) { if (tid < s) red[tid] += red[tid + s]; __syncthreads(); }
  float svt = red[0]; __syncthreads();
  red[tid] = sw; __syncthreads();
  for (int s = 128; s; s >>= 1) { if (tid < s) red[tid] += red[tid + s]; __syncthreads(); }
  if (tid == 0) invsig[m] = sqrtf(svt / red[0]);
}

// ---------------- prep: Wcomb f16 = [Wih | Whh] * inv_sigma ----------------
__global__ __launch_bounds__(256) void prep_wcomb(
    const float* __restrict__ Wih, const float* __restrict__ Whh,
    const float* __restrict__ invsig, _Float16* __restrict__ wcomb) {
  size_t idx4 = ((size_t)blockIdx.x * 256 + threadIdx.x) * 4;
  if (idx4 >= (size_t)2 * 4096 * 2048) return;
  int l = (int)(idx4 >> 23);
  int rem = (int)(idx4 & ((1u << 23) - 1));
  int r = rem >> 11, k = rem & 2047;
  const float* src; float s;
  if (k < 1024) { src = Wih + ((size_t)l << 22) + (size_t)r * 1024 + k; s = invsig[l]; }
  else          { src = Whh + ((size_t)l << 22) + (size_t)r * 1024 + (k - 1024); s = invsig[2 + l]; }
  float4 v = *(const float4*)src;
  half4 o = { (_Float16)(v.x * s), (_Float16)(v.y * s),
              (_Float16)(v.z * s), (_Float16)(v.w * s) };
  *(half4*)(wcomb + idx4) = o;
}

__global__ __launch_bounds__(256) void prep_bias(
    const float* __restrict__ b_ih, const float* __restrict__ b_hh,
    float* __restrict__ bias) {
  int i = blockIdx.x * 256 + threadIdx.x;
  if (i < 8192) bias[i] = b_ih[i] + b_hh[i];
}

__global__ __launch_bounds__(256) void prep_init(
    const float* __restrict__ x0, const float* __restrict__ h0,
    const float* __restrict__ c0, _Float16* __restrict__ Xinit,
    _Float16* __restrict__ H0p0, _Float16* __restrict__ H1p0,
    float* __restrict__ C0, float* __restrict__ C1) {
  int i = blockIdx.x * 256 + threadIdx.x;   // 0..262143
  Xinit[i] = (_Float16)x0[i];
  H0p0[i]  = (_Float16)h0[i];
  H1p0[i]  = (_Float16)h0[262144 + i];
  C0[i] = c0[i];
  C1[i] = c0[262144 + i];
}

// ---------------- the LSTM cell: LDS-staged GEMM + elementwise ----------------
// grid (64,4): 64 h-col chunks of 16, 4 batch chunks of 64. 256 threads, 4 waves.
// Block tile: A = 64 W-rows (4 gates x 16 h-cols) x K, B = 64 batch x K.
// Wave (wr,wc): 32 gate-rows x 32 batch (2x2 of 16x16 MFMA tiles).
// LDS tiles [64][128] halfs, XOR-swizzled: granule' = granule ^ (row&7).
__global__ __launch_bounds__(256) void lstm_cell(
    const _Float16* __restrict__ W,     // [4096][2048] f16, pre-scaled
    const float* __restrict__ bias,     // [4096] (per-layer base)
    const _Float16* __restrict__ xbuf,  // [256][1024] f16
    const _Float16* __restrict__ hbuf,  // [256][1024] f16
    float* __restrict__ cbuf,           // [256][1024] f32 (in-place)
    _Float16* __restrict__ hout,        // [256][1024] f16
    float* __restrict__ yout)           // null, or d_out + t*1024
{
  __shared__ __align__(16) char smem[65536];   // 2 bufs x (A 16K + B 16K)
  const int tid = threadIdx.x;
  const int lane = tid & 63, w = tid >> 6;
  const int wr = w & 1, wc = w >> 1;
  const int lr = lane & 15, lk = lane >> 4;
  const int j0 = blockIdx.x * 16;
  const int bm0 = blockIdx.y * 64;

  const char* Wb = (const char*)W;
  const char* Xb = (const char*)xbuf;
  const char* Hc = (const char*)hbuf;

  // staging descriptors: granule c = q*256+tid; row=c>>4, g16=c&15
  size_t abase[4];   // W row base + swizzled in-slice offset (add bi*256)
  int    brow[4];    // local batch row
  int    bswz[4];    // swizzled in-slice offset for B (add k0b)
  int    dst16[4];   // LDS byte offset of granule within tile
#pragma unroll
  for (int q = 0; q < 4; ++q) {
    int c = q * 256 + tid;
    int row = c >> 4, g16 = c & 15;
    int srcg = (g16 ^ (row & 7)) << 4;
    int grow = (row >> 4) * 1024 + j0 + (row & 15);
    abase[q] = (size_t)grow * 4096 + srcg;
    brow[q] = row; bswz[q] = srcg;
    dst16[q] = c * 16;
  }

  f32x4 acc00 = {0,0,0,0}, acc01 = {0,0,0,0}, acc10 = {0,0,0,0}, acc11 = {0,0,0,0};
  const int ar0 = wr * 32 + lr, ar1 = ar0 + 16;
  const int br0 = wc * 32 + lr, br1 = br0 + 16;

#define STAGE(p, bi) do {                                                     \
    const char* actb = ((bi) < 8) ? Xb : Hc;                                  \
    const size_t k0b = (size_t)((bi) & 7) * 256;                              \
    const size_t ka  = (size_t)(bi) * 256;                                    \
    char* lb = smem + (p) * 32768;                                            \
    _Pragma("unroll")                                                         \
    for (int q = 0; q < 4; ++q) {                                             \
      gload16(Wb + abase[q] + ka, lb + dst16[q]);                             \
      gload16(actb + (size_t)(bm0 + brow[q]) * 2048 + k0b + bswz[q],          \
              lb + 16384 + dst16[q]);                                         \
    }                                                                         \
  } while (0)

#define LDSOFF(row, s) ((row) * 256 + (((((s) << 2) + lk) ^ ((row) & 7)) << 4))

#define COMPUTE(p) do {                                                       \
    const _Float16* Ab = (const _Float16*)(smem + (p) * 32768);               \
    const _Float16* Bb = (const _Float16*)(smem + (p) * 32768 + 16384);       \
    _Pragma("unroll")                                                         \
    for (int s = 0; s < 4; ++s) {                                             \
      half8 a0 = *(const half8*)(Ab + (LDSOFF(ar0, s) >> 1));                 \
      half8 a1 = *(const half8*)(Ab + (LDSOFF(ar1, s) >> 1));                 \
      half8 b0 = *(const half8*)(Bb + (LDSOFF(br0, s) >> 1));                 \
      half8 b1 = *(const half8*)(Bb + (LDSOFF(br1, s) >> 1));                 \
      acc00 = __builtin_amdgcn_mfma_f32_16x16x32_f16(a0, b0, acc00, 0, 0, 0); \
      acc01 = __builtin_amdgcn_mfma_f32_16x16x32_f16(a0, b1, acc01, 0, 0, 0); \
      acc10 = __builtin_amdgcn_mfma_f32_16x16x32_f16(a1, b0, acc10, 0, 0, 0); \
      acc11 = __builtin_amdgcn_mfma_f32_16x16x32_f16(a1, b1, acc11, 0, 0, 0); \
    }                                                                         \
  } while (0)

  STAGE(0, 0);
  __syncthreads();
#pragma unroll 2
  for (int bi = 0; bi < 16; ++bi) {
    const int p = bi & 1;
    if (bi < 15) STAGE(p ^ 1, bi + 1);
    COMPUTE(p);
    __syncthreads();   // also isolates smem reuse as gl below
  }

  // gate exchange through LDS (aliases staging smem — safe after barrier)
  float (*gl)[65] = (float(*)[65])smem;
#pragma unroll
  for (int i = 0; i < 2; ++i) {
    const int rbase = wr * 32 + i * 16 + lk * 4;
    f32x4 v0 = (i == 0) ? acc00 : acc10;
    f32x4 v1 = (i == 0) ? acc01 : acc11;
#pragma unroll
    for (int rr = 0; rr < 4; ++rr) {
      gl[rbase + rr][wc * 32 + lr] = v0[rr];
      gl[rbase + rr][wc * 32 + 16 + lr] = v1[rr];
    }
  }
  __syncthreads();

  // recombine + LSTM elementwise. thread: b = tid>>2, 4 consecutive h-cols.
  {
    const int b = tid >> 2, jj = tid & 3;
    const float* bp = bias + j0 + jj * 4;
    float4 bi4 = *(const float4*)(bp);
    float4 bf4 = *(const float4*)(bp + 1024);
    float4 bg4 = *(const float4*)(bp + 2048);
    float4 bo4 = *(const float4*)(bp + 3072);
    const size_t idx = (size_t)(bm0 + b) * 1024 + j0 + jj * 4;
    float4 c4 = *(const float4*)&cbuf[idx];
    float cn4[4], hn4[4];
    const float* bi_p = &bi4.x; const float* bf_p = &bf4.x;
    const float* bg_p = &bg4.x; const float* bo_p = &bo4.x;
    const float* c_p = &c4.x;
#pragma unroll
    for (int cc = 0; cc < 4; ++cc) {
      const int r = jj * 4 + cc;
      float iv = gl[r][b]      + bi_p[cc];
      float fv = gl[16 + r][b] + bf_p[cc];
      float gv = gl[32 + r][b] + bg_p[cc];
      float ov = gl[48 + r][b] + bo_p[cc];
      float si = 1.f / (1.f + __expf(-iv));
      float sf = 1.f / (1.f + __expf(-fv));
      float so = 1.f / (1.f + __expf(-ov));
      float e2g = __expf(fminf(fmaxf(2.f * gv, -30.f), 30.f));
      float tg = (e2g - 1.f) / (e2g + 1.f);
      float cn = sf * c_p[cc] + si * tg;
      float e2c = __expf(fminf(fmaxf(2.f * cn, -30.f), 30.f));
      float tc = (e2c - 1.f) / (e2c + 1.f);
      cn4[cc] = cn;
      hn4[cc] = so * tc;
    }
    float4 cno = { cn4[0], cn4[1], cn4[2], cn4[3] };
    *(float4*)&cbuf[idx] = cno;
    half4 h4 = { (_Float16)hn4[0], (_Float16)hn4[1],
                 (_Float16)hn4[2], (_Float16)hn4[3] };
    *(half4*)&hout[idx] = h4;
    if (yout) {
      float4 y4 = { hn4[0], hn4[1], hn4[2], hn4[3] };
      *(float4*)&yout[(size_t)(bm0 + b) * (TSZ * HSZ) + j0 + jj * 4] = y4;
    }
  }
#undef STAGE
#undef LDSOFF
#undef COMPUTE
}

extern "C" void kernel_launch(void* const* d_in, const int* in_sizes, int n_in,
                              void* d_out, int out_size, void* d_ws, size_t ws_size,
                              hipStream_t stream) {
  (void)in_sizes; (void)n_in; (void)out_size; (void)ws_size;
  const float* x0   = (const float*)d_in[0];
  const float* h0   = (const float*)d_in[1];
  const float* c0   = (const float*)d_in[2];
  const float* Wih  = (const float*)d_in[3];
  const float* Whh  = (const float*)d_in[4];
  const float* b_ih = (const float*)d_in[5];
  const float* b_hh = (const float*)d_in[6];
  const float* u_ih = (const float*)d_in[7];
  const float* u_hh = (const float*)d_in[8];
  float* out = (float*)d_out;

  char* ws = (char*)d_ws;
  size_t off = 0;
  auto alloc = [&](size_t bytes) -> void* {
    void* p = ws + off;
    off = (off + bytes + 255) & ~(size_t)255;
    return p;
  };
  _Float16* wcomb  = (_Float16*)alloc((size_t)2 * 4096 * 2048 * 2);
  float*    vpart  = (float*)alloc((size_t)4 * 16 * 1024 * 4);
  float*    vraw   = (float*)alloc((size_t)4 * 1024 * 4);
  float*    wv     = (float*)alloc((size_t)4 * 4096 * 4);
  float*    invsig = (float*)alloc(16);
  float*    bias   = (float*)alloc((size_t)2 * 4096 * 4);
  _Float16* Xinit  = (_Float16*)alloc((size_t)262144 * 2);
  _Float16* Hb[2][2];
  for (int a = 0; a < 2; ++a)
    for (int p = 0; p < 2; ++p)
      Hb[a][p] = (_Float16*)alloc((size_t)262144 * 2);
  float* Cb[2];
  Cb[0] = (float*)alloc((size_t)262144 * 4);
  Cb[1] = (float*)alloc((size_t)262144 * 4);

  prep_vraw1<<<256, 256, 0, stream>>>(Wih, Whh, u_ih, u_hh, vpart);
  prep_vraw2<<<16, 256, 0, stream>>>(vpart, vraw);
  prep_wv<<<dim3(1024, 4), 256, 0, stream>>>(Wih, Whh, vraw, wv);
  prep_sig<<<4, 256, 0, stream>>>(vraw, wv, invsig);
  prep_wcomb<<<16384, 256, 0, stream>>>(Wih, Whh, invsig, wcomb);
  prep_bias<<<32, 256, 0, stream>>>(b_ih, b_hh, bias);
  prep_init<<<1024, 256, 0, stream>>>(x0, h0, c0, Xinit, Hb[0][0], Hb[1][0], Cb[0], Cb[1]);

  _Float16* W0 = wcomb;
  _Float16* W1 = wcomb + (size_t)4096 * 2048;

  for (int t = 0; t < TSZ; ++t) {
    int p = t & 1;
    lstm_cell<<<dim3(64, 4), 256, 0, stream>>>(
        W0, bias, (t == 0 ? Xinit : Hb[1][p]), Hb[0][p], Cb[0], Hb[0][p ^ 1], nullptr);
    lstm_cell<<<dim3(64, 4), 256, 0, stream>>>(
        W1, bias + 4096, Hb[0][p ^ 1], Hb[1][p], Cb[1], Hb[1][p ^ 1],
        out + (size_t)t * HSZ);
  }
}

// Round 3
// 2723.435 us; speedup vs baseline: 4.4944x; 1.3634x over previous
//
#include <hip/hip_runtime.h>
#include <hip/hip_bf16.h>

// LSTM decoder: B=256, H=1024, L=2, T=128.
// R3: counted-vmcnt deep pipeline (T3/T4, m201 pattern). 3 LDS buffers
// (96 KB), 2 K-tiles in flight across raw s_barriers; never drains vmcnt
// in the K-loop. Same tiling as R2: 256 blocks (64 j-chunks x 4 batch
// chunks), 4 waves of 32x32 register tiles, BK=128, fused LSTM epilogue.

typedef _Float16 half8 __attribute__((ext_vector_type(8)));
typedef _Float16 half4 __attribute__((ext_vector_type(4)));
typedef float f32x4 __attribute__((ext_vector_type(4)));

#define HSZ 1024
#define BSZ 256
#define TSZ 128

#define AS1 __attribute__((address_space(1)))
#define AS3 __attribute__((address_space(3)))

static __device__ __forceinline__ void gload16(const void* g, void* l) {
  __builtin_amdgcn_global_load_lds((const AS1 unsigned int*)g,
                                   (AS3 unsigned int*)l, 16, 0, 0);
}

// ---------------- prep: vraw = W^T u (two-stage deterministic) ----------------
__global__ __launch_bounds__(256) void prep_vraw1(
    const float* __restrict__ Wih, const float* __restrict__ Whh,
    const float* __restrict__ uih, const float* __restrict__ uhh,
    float* __restrict__ vpart) {
  int bx = blockIdx.x;                 // 256 blocks: m(4) x rc(16) x jc(4)
  int m = bx >> 6, rc = (bx >> 2) & 15, jc = bx & 3;
  int j = jc * 256 + threadIdx.x;
  const float* W = (m < 2 ? Wih : Whh) + ((size_t)(m & 1) << 22);
  const float* u = (m < 2 ? uih : uhh) + (m & 1) * 4096;
  float acc = 0.f;
  int rbase = rc * 256;
  for (int r = 0; r < 256; ++r)
    acc += W[(size_t)(rbase + r) * 1024 + j] * u[rbase + r];
  vpart[(m * 16 + rc) * 1024 + j] = acc;
}

__global__ __launch_bounds__(256) void prep_vraw2(
    const float* __restrict__ vpart, float* __restrict__ vraw) {
  int i = blockIdx.x * 256 + threadIdx.x;   // 0..4095 -> m*1024+j
  int m = i >> 10;
  float acc = 0.f;
  for (int rc = 0; rc < 16; ++rc)
    acc += vpart[(m * 16 + rc) * 1024 + (i & 1023)];
  vraw[i] = acc;
}

// ---------------- prep: wv = W @ vraw ----------------
__global__ __launch_bounds__(256) void prep_wv(
    const float* __restrict__ Wih, const float* __restrict__ Whh,
    const float* __restrict__ vraw, float* __restrict__ wv) {
  int m = blockIdx.y;
  int w = threadIdx.x >> 6, l = threadIdx.x & 63;
  int r = blockIdx.x * 4 + w;
  const float* W = (m < 2 ? Wih : Whh) + ((size_t)(m & 1) << 22) + (size_t)r * 1024;
  const float* v = vraw + m * 1024;
  float acc = 0.f;
  for (int it = 0; it < 4; ++it) {
    int j = it * 256 + l * 4;
    float4 w4 = *(const float4*)(W + j);
    float4 v4 = *(const float4*)(v + j);
    acc += w4.x * v4.x + w4.y * v4.y + w4.z * v4.z + w4.w * v4.w;
  }
  for (int o = 32; o; o >>= 1) acc += __shfl_down(acc, o);
  if (l == 0) wv[m * 4096 + r] = acc;
}

// ---------------- prep: inv_sigma = ||vraw|| / ||wv|| ----------------
__global__ __launch_bounds__(256) void prep_sig(
    const float* __restrict__ vraw, const float* __restrict__ wv,
    float* __restrict__ invsig) {
  int m = blockIdx.x, tid = threadIdx.x;
  __shared__ float red[256];
  float sv = 0.f, sw = 0.f;
  for (int i = tid; i < 1024; i += 256) { float x = vraw[m * 1024 + i]; sv += x * x; }
  for (int i = tid; i < 4096; i += 256) { float x = wv[m * 4096 + i]; sw += x * x; }
  red[tid] = sv; __syncthreads();
  for (int s = 128; s; s >>= 1) { if (tid < s) red[tid] += red[tid + s]; __syncthreads(); }
  float svt = red[0]; __syncthreads();
  red[tid] = sw; __syncthreads();
  for (int s = 128; s; s >>= 1) { if (tid < s) red[tid] += red[tid + s]; __syncthreads(); }
  if (tid == 0) invsig[m] = sqrtf(svt / red[0]);
}

// ---------------- prep: Wcomb f16 = [Wih | Whh] * inv_sigma ----------------
__global__ __launch_bounds__(256) void prep_wcomb(
    const float* __restrict__ Wih, const float* __restrict__ Whh,
    const float* __restrict__ invsig, _Float16* __restrict__ wcomb) {
  size_t idx4 = ((size_t)blockIdx.x * 256 + threadIdx.x) * 4;
  if (idx4 >= (size_t)2 * 4096 * 2048) return;
  int l = (int)(idx4 >> 23);
  int rem = (int)(idx4 & ((1u << 23) - 1));
  int r = rem >> 11, k = rem & 2047;
  const float* src; float s;
  if (k < 1024) { src = Wih + ((size_t)l << 22) + (size_t)r * 1024 + k; s = invsig[l]; }
  else          { src = Whh + ((size_t)l << 22) + (size_t)r * 1024 + (k - 1024); s = invsig[2 + l]; }
  float4 v = *(const float4*)src;
  half4 o = { (_Float16)(v.x * s), (_Float16)(v.y * s),
              (_Float16)(v.z * s), (_Float16)(v.w * s) };
  *(half4*)(wcomb + idx4) = o;
}

__global__ __launch_bounds__(256) void prep_bias(
    const float* __restrict__ b_ih, const float* __restrict__ b_hh,
    float* __restrict__ bias) {
  int i = blockIdx.x * 256 + threadIdx.x;
  if (i < 8192) bias[i] = b_ih[i] + b_hh[i];
}

__global__ __launch_bounds__(256) void prep_init(
    const float* __restrict__ x0, const float* __restrict__ h0,
    const float* __restrict__ c0, _Float16* __restrict__ Xinit,
    _Float16* __restrict__ H0p0, _Float16* __restrict__ H1p0,
    float* __restrict__ C0, float* __restrict__ C1) {
  int i = blockIdx.x * 256 + threadIdx.x;   // 0..262143
  Xinit[i] = (_Float16)x0[i];
  H0p0[i]  = (_Float16)h0[i];
  H1p0[i]  = (_Float16)h0[262144 + i];
  C0[i] = c0[i];
  C1[i] = c0[262144 + i];
}

// ---------------- the LSTM cell: pipelined LDS-staged GEMM + elementwise ------
// grid (64,4): 64 h-col chunks of 16, 4 batch chunks of 64. 256 threads, 4 waves.
// Block tile: A = 64 W-rows (4 gates x 16 h-cols) x K, B = 64 batch x K.
// Wave (wr,wc): 32 gate-rows x 32 batch (2x2 of 16x16 MFMA tiles).
// 3 LDS buffers of 32 KB (BK=128), 2 tiles in flight, counted vmcnt waits.
__global__ __launch_bounds__(256) void lstm_cell(
    const _Float16* __restrict__ W,     // [4096][2048] f16, pre-scaled
    const float* __restrict__ bias,     // [4096] (per-layer base)
    const _Float16* __restrict__ xbuf,  // [256][1024] f16
    const _Float16* __restrict__ hbuf,  // [256][1024] f16
    float* __restrict__ cbuf,           // [256][1024] f32 (in-place)
    _Float16* __restrict__ hout,        // [256][1024] f16
    float* __restrict__ yout)           // null, or d_out + t*1024
{
  __shared__ __align__(16) char smem[98304];   // 3 bufs x (A 16K + B 16K)
  const int tid = threadIdx.x;
  const int lane = tid & 63, w = tid >> 6;
  const int wr = w & 1, wc = w >> 1;
  const int lr = lane & 15, lk = lane >> 4;
  const int j0 = blockIdx.x * 16;
  const int bm0 = blockIdx.y * 64;

  const char* Wb = (const char*)W;
  const char* Xb = (const char*)xbuf;
  const char* Hc = (const char*)hbuf;

  // staging descriptors: granule c = q*256+tid; row=c>>4, g16=c&15
  size_t abase[4];   // W row base + swizzled in-slice offset (add bi*256)
  int    brow[4];    // local batch row
  int    bswz[4];    // swizzled in-slice offset for B (add k0b)
  int    dst16[4];   // LDS byte offset of granule within tile
#pragma unroll
  for (int q = 0; q < 4; ++q) {
    int c = q * 256 + tid;
    int row = c >> 4, g16 = c & 15;
    int srcg = (g16 ^ (row & 7)) << 4;
    int grow = (row >> 4) * 1024 + j0 + (row & 15);
    abase[q] = (size_t)grow * 4096 + srcg;
    brow[q] = row; bswz[q] = srcg;
    dst16[q] = c * 16;
  }

  f32x4 acc00 = {0,0,0,0}, acc01 = {0,0,0,0}, acc10 = {0,0,0,0}, acc11 = {0,0,0,0};
  const int ar0 = wr * 32 + lr, ar1 = ar0 + 16;
  const int br0 = wc * 32 + lr, br1 = br0 + 16;

#define STAGE(p, bi) do {                                                     \
    const char* actb = ((bi) < 8) ? Xb : Hc;                                  \
    const size_t k0b = (size_t)((bi) & 7) * 256;                              \
    const size_t ka  = (size_t)(bi) * 256;                                    \
    char* lb = smem + (p) * 32768;                                            \
    _Pragma("unroll")                                                         \
    for (int q = 0; q < 4; ++q) {                                             \
      gload16(Wb + abase[q] + ka, lb + dst16[q]);                             \
      gload16(actb + (size_t)(bm0 + brow[q]) * 2048 + k0b + bswz[q],          \
              lb + 16384 + dst16[q]);                                         \
    }                                                                         \
  } while (0)

#define LDSOFF(row, s) ((row) * 256 + (((((s) << 2) + lk) ^ ((row) & 7)) << 4))

#define COMPUTE(p) do {                                                       \
    const _Float16* Ab = (const _Float16*)(smem + (p) * 32768);               \
    const _Float16* Bb = (const _Float16*)(smem + (p) * 32768 + 16384);       \
    _Pragma("unroll")                                                         \
    for (int s = 0; s < 4; ++s) {                                             \
      half8 a0 = *(const half8*)(Ab + (LDSOFF(ar0, s) >> 1));                 \
      half8 a1 = *(const half8*)(Ab + (LDSOFF(ar1, s) >> 1));                 \
      half8 b0 = *(const half8*)(Bb + (LDSOFF(br0, s) >> 1));                 \
      half8 b1 = *(const half8*)(Bb + (LDSOFF(br1, s) >> 1));                 \
      acc00 = __builtin_amdgcn_mfma_f32_16x16x32_f16(a0, b0, acc00, 0, 0, 0); \
      acc01 = __builtin_amdgcn_mfma_f32_16x16x32_f16(a0, b1, acc01, 0, 0, 0); \
      acc10 = __builtin_amdgcn_mfma_f32_16x16x32_f16(a1, b0, acc10, 0, 0, 0); \
      acc11 = __builtin_amdgcn_mfma_f32_16x16x32_f16(a1, b1, acc11, 0, 0, 0); \
    }                                                                         \
  } while (0)

#define WAITVM(N) asm volatile("s_waitcnt vmcnt(" #N ")" ::: "memory")
#define BAR() do { asm volatile("" ::: "memory");                             \
    __builtin_amdgcn_s_barrier();                                             \
    asm volatile("" ::: "memory"); } while (0)

  // prologue: tiles 0 and 1 in flight
  STAGE(0, 0);
  STAGE(1, 1);

  // steady state: stage t+2, wait own tile-t loads (2x8 newer in flight),
  // barrier (all waves' tile-t landed), compute t, barrier (read-vs-overwrite).
#define ITER(bi, pb, ps) do {                                                 \
    STAGE(ps, (bi) + 2);                                                      \
    WAITVM(16); BAR();                                                        \
    COMPUTE(pb);                                                              \
    BAR(); } while (0)

  ITER(0, 0, 2);  ITER(1, 1, 0);  ITER(2, 2, 1);  ITER(3, 0, 2);
  ITER(4, 1, 0);  ITER(5, 2, 1);  ITER(6, 0, 2);  ITER(7, 1, 0);
  ITER(8, 2, 1);  ITER(9, 0, 2);  ITER(10, 1, 0); ITER(11, 2, 1);
  ITER(12, 0, 2); ITER(13, 1, 0);
  // tail: no more stages; 8 then 0 loads newer than the awaited tile
  WAITVM(8);  BAR(); COMPUTE(2); BAR();
  WAITVM(0);  BAR(); COMPUTE(0); BAR();

  // gate exchange through LDS (aliases staging smem — safe after barrier)
  float (*gl)[65] = (float(*)[65])smem;
#pragma unroll
  for (int i = 0; i < 2; ++i) {
    const int rbase = wr * 32 + i * 16 + lk * 4;
    f32x4 v0 = (i == 0) ? acc00 : acc10;
    f32x4 v1 = (i == 0) ? acc01 : acc11;
#pragma unroll
    for (int rr = 0; rr < 4; ++rr) {
      gl[rbase + rr][wc * 32 + lr] = v0[rr];
      gl[rbase + rr][wc * 32 + 16 + lr] = v1[rr];
    }
  }
  __syncthreads();

  // recombine + LSTM elementwise. thread: b = tid>>2, 4 consecutive h-cols.
  {
    const int b = tid >> 2, jj = tid & 3;
    const float* bp = bias + j0 + jj * 4;
    float4 bi4 = *(const float4*)(bp);
    float4 bf4 = *(const float4*)(bp + 1024);
    float4 bg4 = *(const float4*)(bp + 2048);
    float4 bo4 = *(const float4*)(bp + 3072);
    const size_t idx = (size_t)(bm0 + b) * 1024 + j0 + jj * 4;
    float4 c4 = *(const float4*)&cbuf[idx];
    float cn4[4], hn4[4];
    const float* bi_p = &bi4.x; const float* bf_p = &bf4.x;
    const float* bg_p = &bg4.x; const float* bo_p = &bo4.x;
    const float* c_p = &c4.x;
#pragma unroll
    for (int cc = 0; cc < 4; ++cc) {
      const int r = jj * 4 + cc;
      float iv = gl[r][b]      + bi_p[cc];
      float fv = gl[16 + r][b] + bf_p[cc];
      float gv = gl[32 + r][b] + bg_p[cc];
      float ov = gl[48 + r][b] + bo_p[cc];
      float si = 1.f / (1.f + __expf(-iv));
      float sf = 1.f / (1.f + __expf(-fv));
      float so = 1.f / (1.f + __expf(-ov));
      float e2g = __expf(fminf(fmaxf(2.f * gv, -30.f), 30.f));
      float tg = (e2g - 1.f) / (e2g + 1.f);
      float cn = sf * c_p[cc] + si * tg;
      float e2c = __expf(fminf(fmaxf(2.f * cn, -30.f), 30.f));
      float tc = (e2c - 1.f) / (e2c + 1.f);
      cn4[cc] = cn;
      hn4[cc] = so * tc;
    }
    float4 cno = { cn4[0], cn4[1], cn4[2], cn4[3] };
    *(float4*)&cbuf[idx] = cno;
    half4 h4 = { (_Float16)hn4[0], (_Float16)hn4[1],
                 (_Float16)hn4[2], (_Float16)hn4[3] };
    *(half4*)&hout[idx] = h4;
    if (yout) {
      float4 y4 = { hn4[0], hn4[1], hn4[2], hn4[3] };
      *(float4*)&yout[(size_t)(bm0 + b) * (TSZ * HSZ) + j0 + jj * 4] = y4;
    }
  }
#undef STAGE
#undef LDSOFF
#undef COMPUTE
#undef WAITVM
#undef BAR
#undef ITER
}

extern "C" void kernel_launch(void* const* d_in, const int* in_sizes, int n_in,
                              void* d_out, int out_size, void* d_ws, size_t ws_size,
                              hipStream_t stream) {
  (void)in_sizes; (void)n_in; (void)out_size; (void)ws_size;
  const float* x0   = (const float*)d_in[0];
  const float* h0   = (const float*)d_in[1];
  const float* c0   = (const float*)d_in[2];
  const float* Wih  = (const float*)d_in[3];
  const float* Whh  = (const float*)d_in[4];
  const float* b_ih = (const float*)d_in[5];
  const float* b_hh = (const float*)d_in[6];
  const float* u_ih = (const float*)d_in[7];
  const float* u_hh = (const float*)d_in[8];
  float* out = (float*)d_out;

  char* ws = (char*)d_ws;
  size_t off = 0;
  auto alloc = [&](size_t bytes) -> void* {
    void* p = ws + off;
    off = (off + bytes + 255) & ~(size_t)255;
    return p;
  };
  _Float16* wcomb  = (_Float16*)alloc((size_t)2 * 4096 * 2048 * 2);
  float*    vpart  = (float*)alloc((size_t)4 * 16 * 1024 * 4);
  float*    vraw   = (float*)alloc((size_t)4 * 1024 * 4);
  float*    wv     = (float*)alloc((size_t)4 * 4096 * 4);
  float*    invsig = (float*)alloc(16);
  float*    bias   = (float*)alloc((size_t)2 * 4096 * 4);
  _Float16* Xinit  = (_Float16*)alloc((size_t)262144 * 2);
  _Float16* Hb[2][2];
  for (int a = 0; a < 2; ++a)
    for (int p = 0; p < 2; ++p)
      Hb[a][p] = (_Float16*)alloc((size_t)262144 * 2);
  float* Cb[2];
  Cb[0] = (float*)alloc((size_t)262144 * 4);
  Cb[1] = (float*)alloc((size_t)262144 * 4);

  prep_vraw1<<<256, 256, 0, stream>>>(Wih, Whh, u_ih, u_hh, vpart);
  prep_vraw2<<<16, 256, 0, stream>>>(vpart, vraw);
  prep_wv<<<dim3(1024, 4), 256, 0, stream>>>(Wih, Whh, vraw, wv);
  prep_sig<<<4, 256, 0, stream>>>(vraw, wv, invsig);
  prep_wcomb<<<16384, 256, 0, stream>>>(Wih, Whh, invsig, wcomb);
  prep_bias<<<32, 256, 0, stream>>>(b_ih, b_hh, bias);
  prep_init<<<1024, 256, 0, stream>>>(x0, h0, c0, Xinit, Hb[0][0], Hb[1][0], Cb[0], Cb[1]);

  _Float16* W0 = wcomb;
  _Float16* W1 = wcomb + (size_t)4096 * 2048;

  for (int t = 0; t < TSZ; ++t) {
    int p = t & 1;
    lstm_cell<<<dim3(64, 4), 256, 0, stream>>>(
        W0, bias, (t == 0 ? Xinit : Hb[1][p]), Hb[0][p], Cb[0], Hb[0][p ^ 1], nullptr);
    lstm_cell<<<dim3(64, 4), 256, 0, stream>>>(
        W1, bias + 4096, Hb[0][p ^ 1], Hb[1][p], Cb[1], Hb[1][p ^ 1],
        out + (size_t)t * HSZ);
  }
}